// Round 2
// baseline (6561.263 us; speedup 1.0000x reference)
//
#include <hip/hip_runtime.h>

#define NB 64
#define NH 128

// ---- ws layout (float offsets) ----
#define WS_WX    0                       // 768*64            = 49152
#define WS_WT    49152                   // 320*1024          = 327680
#define WS_BIAS  376832                  // 1024
#define WS_HNEW  377856                  // 32*64*256         = 524288
#define WS_HC    902144                  // 32*32*64*128      = 8388608
#define WS_FLAGS 9290752                 // ints: 32 rowdone + 1024 gatecnt + 1024 compcnt
// total ≈ 37.2 MB

// W_x = W_ih[:, :128] @ We   (768x64): fold embedding into gate weights
__global__ __launch_bounds__(256) void k_build_wx(
    const float* __restrict__ W_ih, const float* __restrict__ We,
    float* __restrict__ Wx)
{
    __shared__ float WeS[128][64];
    const int tid = threadIdx.x;
    #pragma unroll
    for (int q = 0; q < 8; ++q) {
        int p = q*256 + tid;            // 2048 float4 = 8192 floats
        int e = p >> 4, k4 = p & 15;
        *(float4*)&WeS[e][k4*4] = *(const float4*)&We[e*64 + k4*4];
    }
    __syncthreads();
    int idx = blockIdx.x*256 + tid;     // 49152 outputs -> 192 blocks
    int r = idx >> 6, k = idx & 63;
    float acc = 0.f;
    #pragma unroll 4
    for (int e = 0; e < 128; ++e) acc = fmaf(W_ih[r*128 + e], WeS[e][k], acc);
    Wx[idx] = acc;
}

// bias4[o'], o'=4c+g4: fused gate bias incl. embedding bias folded through W_ih
__global__ __launch_bounds__(256) void k_build_bias(
    const float* __restrict__ b_ih, const float* __restrict__ b_hh,
    const float* __restrict__ W_ih, const float* __restrict__ be,
    float* __restrict__ bias4)
{
    int op = blockIdx.x*256 + threadIdx.x;   // 1024 -> 4 blocks
    int c = op >> 2, g4 = op & 3;
    int row = (g4 == 0) ? c : (g4 == 1) ? 256 + c : 512 + c;
    float bx = b_ih[row];
    #pragma unroll 4
    for (int e = 0; e < 128; ++e) bx = fmaf(W_ih[row*128 + e], be[e], bx);
    float v;
    if (g4 == 0)      v = bx + b_hh[c];
    else if (g4 == 1) v = bx + b_hh[256 + c];
    else if (g4 == 2) v = bx;                 // xn bias
    else              v = b_hh[512 + c];      // hn bias
    bias4[op] = v;
}

// Fused gate-interleaved weight Wt[k][o'], k=320 = [x(64) | h_row(128) | h_col(128)]
__global__ __launch_bounds__(256) void k_build_wt(
    const float* __restrict__ Wx, const float* __restrict__ W_hh,
    float* __restrict__ Wt)
{
    int idx = blockIdx.x*256 + threadIdx.x;  // 320*1024 -> 1280 blocks
    int k = idx >> 10, op = idx & 1023;
    int c = op >> 2, g4 = op & 3;
    float v;
    if (g4 == 0)      v = (k < 64) ? Wx[c*64 + k]         : W_hh[c*256 + k - 64];
    else if (g4 == 1) v = (k < 64) ? Wx[(256+c)*64 + k]   : W_hh[(256+c)*256 + k - 64];
    else if (g4 == 2) v = (k < 64) ? Wx[(512+c)*64 + k]   : 0.f;
    else              v = (k < 64) ? 0.f                  : W_hh[(512+c)*256 + k - 64];
    Wt[idx] = v;
}

__device__ __forceinline__ int ldacq(int* p) {
    return __hip_atomic_load(p, __ATOMIC_ACQUIRE, __HIP_MEMORY_SCOPE_AGENT);
}

// Persistent 2D-GRU wavefront. 512 WGs: row i = blockIdx&31, slice s = blockIdx>>5.
// Row i processes columns j=0..31 sequentially, gated on rowdone[i-1] (flag sync).
__global__ __launch_bounds__(256) void k_grid(
    const float* __restrict__ x,  const float* __restrict__ Wt,
    const float* __restrict__ bias4, const float* __restrict__ Wc,
    const float* __restrict__ bcb,
    float* __restrict__ hnew, float* __restrict__ hc,
    int* __restrict__ flags, float* __restrict__ out)
{
    __shared__ __align__(16) float As[64][72];   // [k][b] transposed A chunk
    __shared__ __align__(16) float Ws[64][64];   // [k][o'_local]
    int* rowdone = flags;
    int* gatecnt = flags + 32;
    int* compcnt = flags + 32 + 1024;
    const int i   = blockIdx.x & 31;
    const int s   = blockIdx.x >> 5;
    const int tid = threadIdx.x;
    const int bg  = tid >> 4, og = tid & 15;     // gates: 4 b-rows x 1 channel (4 o')
    const int c   = s*16 + og;                   // state channel 0..255
    const float4 bv = *(const float4*)&bias4[s*64 + og*4];
    const int oc  = s*8 + (tid & 7);             // compress: output col
    const int b0  = (tid >> 3) * 2;              // compress: 2 batch rows
    const float bcv = bcb[oc];

    for (int j = 0; j < 32; ++j) {
        const int ij = i*32 + j;
        if (i > 0) {                             // wait for h_c(i-1, j)
            if (tid == 0)
                while (ldacq(&rowdone[i-1]) < j+1) __builtin_amdgcn_s_sleep(1);
            __syncthreads();
        }
        float acc[4][4];
        #pragma unroll
        for (int r = 0; r < 4; ++r) { acc[r][0]=bv.x; acc[r][1]=bv.y; acc[r][2]=bv.z; acc[r][3]=bv.w; }

        for (int kc = 0; kc < 5; ++kc) {         // K = 5 chunks of 64
            #pragma unroll
            for (int q = 0; q < 4; ++q) {        // stage A chunk (transposed, zero-fill edges)
                int p = q*256 + tid;
                int b = p >> 4, k4 = p & 15;
                float4 v = make_float4(0.f, 0.f, 0.f, 0.f);
                if (kc == 0) {
                    v = *(const float4*)&x[((b*32 + i)*32 + j)*64 + k4*4];
                } else if (kc <= 2) {
                    if (i > 0) v = *(const float4*)&hc[(((i-1)*32 + j)*64 + b)*128 + (kc-1)*64 + k4*4];
                } else {
                    if (j > 0) v = *(const float4*)&hc[((i*32 + (j-1))*64 + b)*128 + (kc-3)*64 + k4*4];
                }
                As[k4*4+0][b] = v.x; As[k4*4+1][b] = v.y;
                As[k4*4+2][b] = v.z; As[k4*4+3][b] = v.w;
            }
            #pragma unroll
            for (int q = 0; q < 4; ++q) {        // stage W chunk
                int p = q*256 + tid;
                int kl = p >> 4, c4 = p & 15;
                *(float4*)&Ws[kl][c4*4] = *(const float4*)&Wt[(kc*64 + kl)*1024 + s*64 + c4*4];
            }
            __syncthreads();
            #pragma unroll 4
            for (int k = 0; k < 64; ++k) {
                float4 a = *(const float4*)&As[k][bg*4];
                float4 w = *(const float4*)&Ws[k][og*4];
                float av[4] = {a.x, a.y, a.z, a.w};
                float wv[4] = {w.x, w.y, w.z, w.w};
                #pragma unroll
                for (int r = 0; r < 4; ++r)
                    #pragma unroll
                    for (int cc = 0; cc < 4; ++cc)
                        acc[r][cc] = fmaf(av[r], wv[cc], acc[r][cc]);
            }
            __syncthreads();
        }
        // gate nonlinearities -> hnew
        #pragma unroll
        for (int r = 0; r < 4; ++r) {
            const int b = bg*4 + r;
            float rg = 1.f/(1.f + __expf(-acc[r][0]));
            float zg = 1.f/(1.f + __expf(-acc[r][1]));
            float e2 = __expf(2.f*(acc[r][2] + rg*acc[r][3]));
            float ng = 1.f - 2.f/(e2 + 1.f);
            float hval = 0.f;
            if (c < NH) { if (i > 0) hval = hc[(((i-1)*32 + j)*64 + b)*128 + c]; }
            else        { if (j > 0) hval = hc[((i*32 + (j-1))*64 + b)*128 + (c - NH)]; }
            hnew[i*16384 + b*256 + c] = (1.f - zg)*ng + zg*hval;
        }
        // intra-cell barrier: all 16 slices' hnew visible before compress
        __syncthreads();
        if (tid == 0) {
            __hip_atomic_fetch_add(&gatecnt[ij], 1, __ATOMIC_RELEASE, __HIP_MEMORY_SCOPE_AGENT);
            while (ldacq(&gatecnt[ij]) < 16) __builtin_amdgcn_s_sleep(1);
        }
        __syncthreads();
        // compress: h_c = hnew @ Wc.T + bc  (this WG: 8 o-cols x all 64 b)
        {
            const float* hrow = hnew + i*16384;
            float a0 = bcv, a1 = bcv;
            #pragma unroll 4
            for (int k4 = 0; k4 < 64; ++k4) {
                float4 w = *(const float4*)&Wc[oc*256 + k4*4];
                float4 p = *(const float4*)&hrow[b0*256 + k4*4];
                float4 q = *(const float4*)&hrow[(b0+1)*256 + k4*4];
                a0 += w.x*p.x + w.y*p.y + w.z*p.z + w.w*p.w;
                a1 += w.x*q.x + w.y*q.y + w.z*q.z + w.w*q.w;
            }
            hc[ij*8192 + b0*128 + oc]     = a0;
            hc[ij*8192 + (b0+1)*128 + oc] = a1;
            if (ij == 1023) { out[b0*128 + oc] = a0; out[(b0+1)*128 + oc] = a1; }
        }
        // intra-cell barrier #2: hc(i,j) complete; publish to row i+1
        __syncthreads();
        if (tid == 0) {
            __hip_atomic_fetch_add(&compcnt[ij], 1, __ATOMIC_RELEASE, __HIP_MEMORY_SCOPE_AGENT);
            while (ldacq(&compcnt[ij]) < 16) __builtin_amdgcn_s_sleep(1);
            if (s == 0)
                __hip_atomic_store(&rowdone[i], j+1, __ATOMIC_RELEASE, __HIP_MEMORY_SCOPE_AGENT);
        }
        __syncthreads();
    }
}

extern "C" void kernel_launch(void* const* d_in, const int* in_sizes, int n_in,
                              void* d_out, int out_size, void* d_ws, size_t ws_size,
                              hipStream_t stream)
{
    const float* x    = (const float*)d_in[0];
    const float* We   = (const float*)d_in[1];
    const float* be   = (const float*)d_in[2];
    const float* W_ih = (const float*)d_in[3];
    const float* b_ih = (const float*)d_in[4];
    const float* W_hh = (const float*)d_in[5];
    const float* b_hh = (const float*)d_in[6];
    const float* Wc   = (const float*)d_in[7];
    const float* bc   = (const float*)d_in[8];
    float* ws    = (float*)d_ws;
    float* Wx    = ws + WS_WX;
    float* Wt    = ws + WS_WT;
    float* bias4 = ws + WS_BIAS;
    float* hnew  = ws + WS_HNEW;
    float* hc    = ws + WS_HC;
    int*   flags = (int*)(ws + WS_FLAGS);
    float* out   = (float*)d_out;

    k_build_wx<<<192, 256, 0, stream>>>(W_ih, We, Wx);
    k_build_bias<<<4, 256, 0, stream>>>(b_ih, b_hh, W_ih, be, bias4);
    k_build_wt<<<1280, 256, 0, stream>>>(Wx, W_hh, Wt);
    hipMemsetAsync(flags, 0, (32 + 1024 + 1024)*sizeof(int), stream);
    k_grid<<<512, 256, 0, stream>>>(x, Wt, bias4, Wc, bc, hnew, hc, flags, out);
}

// Round 3
// 3018.629 us; speedup vs baseline: 2.1736x; 2.1736x over previous
//
#include <hip/hip_runtime.h>

#define NB 64
#define NH 128

typedef unsigned long long ull;

// ---- ws layout (float offsets) ----
#define WS_WX    0                       // 768*64    = 49152
#define WS_WT    49152                   // 320*1024  = 327680
#define WS_BIAS  376832                  // 1024
#define WS_HNEW  377856                  // 32*256*64 = 524288
#define WS_HC    902144                  // 1024*64*128 = 8388608
#define WS_FLAGS 9290752                 // ints: 32 rowdone + 1024 gcnt + 1024 ccnt
// total ≈ 37.2 MB

// ---------------- prep kernels ----------------

// W_x = W_ih[:, :128] @ We   (768x64): fold embedding into gate weights
__global__ __launch_bounds__(256) void k_build_wx(
    const float* __restrict__ W_ih, const float* __restrict__ We,
    float* __restrict__ Wx)
{
    __shared__ float WeS[128][64];
    const int tid = threadIdx.x;
    #pragma unroll
    for (int q = 0; q < 8; ++q) {
        int p = q*256 + tid;
        int e = p >> 4, k4 = p & 15;
        *(float4*)&WeS[e][k4*4] = *(const float4*)&We[e*64 + k4*4];
    }
    __syncthreads();
    int idx = blockIdx.x*256 + tid;     // 49152 outputs -> 192 blocks
    int r = idx >> 6, k = idx & 63;
    float acc = 0.f;
    #pragma unroll 4
    for (int e = 0; e < 128; ++e) acc = fmaf(W_ih[r*128 + e], WeS[e][k], acc);
    Wx[idx] = acc;
}

// bias4[o'], o'=4c+g4 (embedding bias folded through W_ih)
__global__ __launch_bounds__(256) void k_build_bias(
    const float* __restrict__ b_ih, const float* __restrict__ b_hh,
    const float* __restrict__ W_ih, const float* __restrict__ be,
    float* __restrict__ bias4)
{
    int op = blockIdx.x*256 + threadIdx.x;   // 1024 -> 4 blocks
    int c = op >> 2, g4 = op & 3;
    int row = (g4 == 0) ? c : (g4 == 1) ? 256 + c : 512 + c;
    float bx = b_ih[row];
    #pragma unroll 4
    for (int e = 0; e < 128; ++e) bx = fmaf(W_ih[row*128 + e], be[e], bx);
    float v;
    if (g4 == 0)      v = bx + b_hh[c];
    else if (g4 == 1) v = bx + b_hh[256 + c];
    else if (g4 == 2) v = bx;
    else              v = b_hh[512 + c];
    bias4[op] = v;
}

// Fused gate-interleaved weight Wt[k][o'], k=320 = [x(64) | h_row(128) | h_col(128)]
__global__ __launch_bounds__(256) void k_build_wt(
    const float* __restrict__ Wx, const float* __restrict__ W_hh,
    float* __restrict__ Wt)
{
    int idx = blockIdx.x*256 + threadIdx.x;  // 320*1024 -> 1280 blocks
    int k = idx >> 10, op = idx & 1023;
    int c = op >> 2, g4 = op & 3;
    float v;
    if (g4 == 0)      v = (k < 64) ? Wx[c*64 + k]         : W_hh[c*256 + k - 64];
    else if (g4 == 1) v = (k < 64) ? Wx[(256+c)*64 + k]   : W_hh[(256+c)*256 + k - 64];
    else if (g4 == 2) v = (k < 64) ? Wx[(512+c)*64 + k]   : 0.f;
    else              v = (k < 64) ? 0.f                  : W_hh[(512+c)*256 + k - 64];
    Wt[idx] = v;
}

// ---------------- coherent access helpers (LLC-serialized, no cache inv) ----------------
__device__ __forceinline__ int ldrlx(const int* p) {
    return __hip_atomic_load(p, __ATOMIC_RELAXED, __HIP_MEMORY_SCOPE_AGENT);
}
__device__ __forceinline__ ull ald64(const void* p) {
    return __hip_atomic_load((const ull*)p, __ATOMIC_RELAXED, __HIP_MEMORY_SCOPE_AGENT);
}
__device__ __forceinline__ void ast64(void* p, float a, float b) {
    union { float f[2]; ull u; } v; v.f[0] = a; v.f[1] = b;
    __hip_atomic_store((ull*)p, v.u, __ATOMIC_RELAXED, __HIP_MEMORY_SCOPE_AGENT);
}
__device__ __forceinline__ void ast32(void* p, float a) {
    __hip_atomic_store((float*)p, a, __ATOMIC_RELAXED, __HIP_MEMORY_SCOPE_AGENT);
}
__device__ __forceinline__ float2 up64(ull u) {
    union { ull u; float f[2]; } v; v.u = u;
    return make_float2(v.f[0], v.f[1]);
}

// ---------------- persistent 2D-GRU wavefront ----------------
// 512 WGs: row i = blockIdx&31, channel-slice s = blockIdx>>5 (16 channels each).
__global__ __launch_bounds__(256, 2) void k_grid(
    const float* __restrict__ x,  const float* __restrict__ Wt,
    const float* __restrict__ bias4, const float* __restrict__ Wc,
    const float* __restrict__ bcb,
    float* __restrict__ hnew, float* __restrict__ hc,
    int* __restrict__ flags, float* __restrict__ out)
{
    __shared__ __align__(16) float As[64][68];   // [b][k_chunk], stride 68 (16B-aligned rows)
    __shared__ __align__(16) float Ws[64][64];   // [k][o'_local]
    __shared__ __align__(16) float WcS[256][8];  // compress weight slice [ch][oc_local]
    int* rowdone = flags;
    int* gcnt    = flags + 32;
    int* ccnt    = flags + 32 + 1024;

    const int i   = blockIdx.x & 31;
    const int s   = blockIdx.x >> 5;
    const int tid = threadIdx.x;
    const int bg  = tid >> 4, og = tid & 15;     // gates: 4 b-rows x 1 channel (4 o')
    const int c   = s*16 + og;                   // state channel 0..255
    const int kcb = (c < 128) ? 1 + (c >> 6) : 3 + ((c - 128) >> 6);  // chunk holding hval
    const int klb = c & 63;
    const float4 bv = *(const float4*)&bias4[s*64 + og*4];
    const int ocl = tid & 7, oc = s*8 + ocl;     // compress mapping
    const int b0  = (tid >> 3) * 2;
    const float bcv = bcb[oc];

    // stage compress weight slice once (persists across all 32 cells)
    #pragma unroll
    for (int q = 0; q < 8; ++q) {
        int idx = q*256 + tid;
        int ch = idx & 255, ol = idx >> 8;
        WcS[ch][ol] = Wc[(s*8 + ol)*256 + ch];
    }

    float* hnewp = hnew + i*16384;

    for (int j = 0; j < 32; ++j) {
        const int ij = i*32 + j;
        // ---- top wait: own row through col j-1 compressed; row above through col j ----
        if (tid == 0) {
            if (j > 0) while (ldrlx(&rowdone[i])   < j)     __builtin_amdgcn_s_sleep(1);
            if (i > 0) while (ldrlx(&rowdone[i-1]) < j + 1) __builtin_amdgcn_s_sleep(1);
        }
        __syncthreads();

        const float* hrowp = hc + (((i-1)*32 + j)     * 8192);
        const float* hcolp = hc + ((i*32 + (j-1)) * 8192);

        float acc[4][4];
        #pragma unroll
        for (int r = 0; r < 4; ++r) { acc[r][0]=bv.x; acc[r][1]=bv.y; acc[r][2]=bv.z; acc[r][3]=bv.w; }
        float hval[4];

        for (int kc = 0; kc < 5; ++kc) {
            // ---- stage A chunk [64 b][64 k] ----
            #pragma unroll
            for (int q = 0; q < 4; ++q) {
                int idx = q*256 + tid;
                int b = idx >> 4, k4 = idx & 15;
                float4 v = make_float4(0.f, 0.f, 0.f, 0.f);
                if (kc == 0) {
                    v = *(const float4*)&x[((b*32 + i)*32 + j)*64 + k4*4];
                } else {
                    const float* src = (kc <= 2) ? hrowp : hcolp;
                    const bool ok = (kc <= 2) ? (i > 0) : (j > 0);
                    if (ok) {
                        int off = b*128 + ((kc-1)&1)*64 + k4*4;
                        float2 lo = up64(ald64(&src[off]));
                        float2 hi = up64(ald64(&src[off+2]));
                        v = make_float4(lo.x, lo.y, hi.x, hi.y);
                    }
                }
                *(float4*)&As[b][k4*4] = v;
            }
            // ---- stage W chunk [64 k][64 o'] ----
            #pragma unroll
            for (int q = 0; q < 4; ++q) {
                int idx = q*256 + tid;
                int kl = idx >> 4, c4 = idx & 15;
                *(float4*)&Ws[kl][c4*4] = *(const float4*)&Wt[(kc*64 + kl)*1024 + s*64 + c4*4];
            }
            __syncthreads();
            if (kc == kcb) {      // capture h state for z-blend from staged chunk
                #pragma unroll
                for (int r = 0; r < 4; ++r) hval[r] = As[bg*4 + r][klb];
            }
            // ---- FMA: 64k x (4b x 4o') per thread ----
            #pragma unroll
            for (int kq = 0; kq < 16; ++kq) {
                float4 a0 = *(const float4*)&As[bg*4+0][kq*4];
                float4 a1 = *(const float4*)&As[bg*4+1][kq*4];
                float4 a2 = *(const float4*)&As[bg*4+2][kq*4];
                float4 a3 = *(const float4*)&As[bg*4+3][kq*4];
                float4 w0 = *(const float4*)&Ws[kq*4+0][og*4];
                float4 w1 = *(const float4*)&Ws[kq*4+1][og*4];
                float4 w2 = *(const float4*)&Ws[kq*4+2][og*4];
                float4 w3 = *(const float4*)&Ws[kq*4+3][og*4];
                float av[4][4] = {{a0.x,a0.y,a0.z,a0.w},{a1.x,a1.y,a1.z,a1.w},
                                  {a2.x,a2.y,a2.z,a2.w},{a3.x,a3.y,a3.z,a3.w}};
                float wv[4][4] = {{w0.x,w0.y,w0.z,w0.w},{w1.x,w1.y,w1.z,w1.w},
                                  {w2.x,w2.y,w2.z,w2.w},{w3.x,w3.y,w3.z,w3.w}};
                #pragma unroll
                for (int kk = 0; kk < 4; ++kk)
                    #pragma unroll
                    for (int r = 0; r < 4; ++r)
                        #pragma unroll
                        for (int cc = 0; cc < 4; ++cc)
                            acc[r][cc] = fmaf(av[r][kk], wv[kk][cc], acc[r][cc]);
            }
            __syncthreads();
        }

        // ---- gate nonlinearities -> hnew[c][b] (coherent stores) ----
        float hn[4];
        #pragma unroll
        for (int r = 0; r < 4; ++r) {
            float rg = 1.f/(1.f + __expf(-acc[r][0]));
            float zg = 1.f/(1.f + __expf(-acc[r][1]));
            float e2 = __expf(2.f*(acc[r][2] + rg*acc[r][3]));
            float ng = 1.f - 2.f/(e2 + 1.f);
            hn[r] = (1.f - zg)*ng + zg*hval[r];
        }
        ast64(&hnewp[c*64 + bg*4],     hn[0], hn[1]);
        ast64(&hnewp[c*64 + bg*4 + 2], hn[2], hn[3]);

        // ---- sibling barrier: all 16 slices' hnew at LLC ----
        __syncthreads();                           // drains vmcnt for all waves
        if (tid == 0) {
            __hip_atomic_fetch_add(&gcnt[ij], 1, __ATOMIC_ACQ_REL, __HIP_MEMORY_SCOPE_AGENT);
            while (ldrlx(&gcnt[ij]) < 16) __builtin_amdgcn_s_sleep(1);
        }
        __syncthreads();

        // ---- compress: h_c = hnew @ Wc.T + bc  (8 oc x 64 b per WG) ----
        float a0 = bcv, a1 = bcv;
        #pragma unroll 4
        for (int ch = 0; ch < 256; ++ch) {
            float2 f = up64(ald64(&hnewp[ch*64 + b0]));
            float w = WcS[ch][ocl];
            a0 = fmaf(w, f.x, a0);
            a1 = fmaf(w, f.y, a1);
        }
        ast32(&hc[ij*8192 + b0*128 + oc],     a0);
        ast32(&hc[ij*8192 + (b0+1)*128 + oc], a1);
        if (ij == 1023) { out[b0*128 + oc] = a0; out[(b0+1)*128 + oc] = a1; }

        // ---- publish: last arriver sets rowdone[i] = j+1 ----
        __syncthreads();                           // drains all waves' hc stores
        if (tid == 0) {
            int old = __hip_atomic_fetch_add(&ccnt[ij], 1, __ATOMIC_ACQ_REL, __HIP_MEMORY_SCOPE_AGENT);
            if (old == 15)
                __hip_atomic_store(&rowdone[i], j + 1, __ATOMIC_RELEASE, __HIP_MEMORY_SCOPE_AGENT);
        }
    }
}

extern "C" void kernel_launch(void* const* d_in, const int* in_sizes, int n_in,
                              void* d_out, int out_size, void* d_ws, size_t ws_size,
                              hipStream_t stream)
{
    const float* x    = (const float*)d_in[0];
    const float* We   = (const float*)d_in[1];
    const float* be   = (const float*)d_in[2];
    const float* W_ih = (const float*)d_in[3];
    const float* b_ih = (const float*)d_in[4];
    const float* W_hh = (const float*)d_in[5];
    const float* b_hh = (const float*)d_in[6];
    const float* Wc   = (const float*)d_in[7];
    const float* bc   = (const float*)d_in[8];
    float* ws    = (float*)d_ws;
    float* Wx    = ws + WS_WX;
    float* Wt    = ws + WS_WT;
    float* bias4 = ws + WS_BIAS;
    float* hnew  = ws + WS_HNEW;
    float* hc    = ws + WS_HC;
    int*   flags = (int*)(ws + WS_FLAGS);
    float* out   = (float*)d_out;

    k_build_wx<<<192, 256, 0, stream>>>(W_ih, We, Wx);
    k_build_bias<<<4, 256, 0, stream>>>(b_ih, b_hh, W_ih, be, bias4);
    k_build_wt<<<1280, 256, 0, stream>>>(Wx, W_hh, Wt);
    hipMemsetAsync(flags, 0, (32 + 1024 + 1024)*sizeof(int), stream);
    k_grid<<<512, 256, 0, stream>>>(x, Wt, bias4, Wc, bc, hnew, hc, flags, out);
}

// Round 4
// 1120.299 us; speedup vs baseline: 5.8567x; 2.6945x over previous
//
#include <hip/hip_runtime.h>

typedef _Float16 half8 __attribute__((ext_vector_type(8)));
typedef float f32x4 __attribute__((ext_vector_type(4)));
typedef unsigned long long ull;

// ---- ws layout (byte offsets) ----
#define OFF_WTH   0u          // WtH  fp16 [1024][320] = 655360
#define OFF_WCH   655360u     // WcH  fp16 [128][256]  = 65536
#define OFF_BIASG 720896u     // biasG f32 [1024]      = 4096
#define OFF_WX    724992u     // Wx   f32  [768][64]   = 196608
#define OFF_XH    921600u     // xH   fp16 [1024][64][64] = 8388608
#define OFF_HCF   9310208u    // hcF  f32  [2][32][64][128] = 2097152
#define OFF_HCH   11407360u   // hcH  fp16 [2][32][64][128] = 1048576
#define OFF_HNX   12455936u   // hnX  fp16 [32][2][64][256] = 2097152
#define OFF_FLAGS 14553088u   // gcnt[1024] + ccnt[1024] ints = 8192
// total ≈ 14.56 MB

// ---------------- coherent helpers (LLC-visible, bypass L1, no cache inv) ---
__device__ __forceinline__ int ldrlx(const int* p) {
    return __hip_atomic_load(p, __ATOMIC_RELAXED, __HIP_MEMORY_SCOPE_AGENT);
}
__device__ __forceinline__ ull ald64(const void* p) {
    return __hip_atomic_load((const ull*)p, __ATOMIC_RELAXED, __HIP_MEMORY_SCOPE_AGENT);
}
__device__ __forceinline__ void ast64(void* p, ull v) {
    __hip_atomic_store((ull*)p, v, __ATOMIC_RELAXED, __HIP_MEMORY_SCOPE_AGENT);
}
__device__ __forceinline__ void ast32u(void* p, unsigned v) {
    __hip_atomic_store((unsigned*)p, v, __ATOMIC_RELAXED, __HIP_MEMORY_SCOPE_AGENT);
}

// ---------------- prep kernels ----------------

// Wx = W_ih[:, :128] @ We   (768x64) fp32
__global__ __launch_bounds__(256) void k_build_wx(
    const float* __restrict__ W_ih, const float* __restrict__ We,
    float* __restrict__ Wx)
{
    __shared__ float WeS[128][64];
    const int tid = threadIdx.x;
    #pragma unroll
    for (int q = 0; q < 8; ++q) {
        int p = q*256 + tid;
        int e = p >> 4, k4 = p & 15;
        *(float4*)&WeS[e][k4*4] = *(const float4*)&We[e*64 + k4*4];
    }
    __syncthreads();
    int idx = blockIdx.x*256 + tid;     // 49152 -> 192 blocks
    int r = idx >> 6, k = idx & 63;
    float acc = 0.f;
    #pragma unroll 4
    for (int e = 0; e < 128; ++e) acc = fmaf(W_ih[r*128 + e], WeS[e][k], acc);
    Wx[idx] = acc;
}

// WtH fp16 [o'=g*256+c][k=320 : x(64)|h(256)]
__global__ __launch_bounds__(256) void k_prep_wt(
    const float* __restrict__ Wx, const float* __restrict__ W_hh,
    _Float16* __restrict__ WtH)
{
    int row = blockIdx.x;               // 1024
    int g = row >> 8, c = row & 255;
    for (int k = threadIdx.x; k < 320; k += 256) {
        float v;
        if (k < 64) v = (g == 3) ? 0.f : Wx[(g*256 + c)*64 + k];
        else if (g == 2) v = 0.f;
        else { int rr = (g == 3) ? (512 + c) : (g*256 + c); v = W_hh[rr*256 + (k - 64)]; }
        WtH[row*320 + k] = (_Float16)v;
    }
}

// biasG f32 [g*256+c], embedding bias folded
__global__ __launch_bounds__(256) void k_prep_bias(
    const float* __restrict__ b_ih, const float* __restrict__ b_hh,
    const float* __restrict__ W_ih, const float* __restrict__ be,
    float* __restrict__ biasG)
{
    int row = blockIdx.x*256 + threadIdx.x;   // 1024
    int g = row >> 8, c = row & 255;
    float v;
    if (g < 3) {
        int r = g*256 + c;
        float bx = b_ih[r];
        #pragma unroll 4
        for (int e = 0; e < 128; ++e) bx = fmaf(W_ih[r*128 + e], be[e], bx);
        v = (g == 0) ? bx + b_hh[c] : (g == 1) ? bx + b_hh[256 + c] : bx;
    } else v = b_hh[512 + c];
    biasG[row] = v;
}

__global__ __launch_bounds__(256) void k_prep_wc(
    const float* __restrict__ Wc, _Float16* __restrict__ WcH)
{
    int i4 = (blockIdx.x*256 + threadIdx.x)*4;   // 32768 elems -> 32 blocks
    float4 v = *(const float4*)&Wc[i4];
    WcH[i4+0] = (_Float16)v.x; WcH[i4+1] = (_Float16)v.y;
    WcH[i4+2] = (_Float16)v.z; WcH[i4+3] = (_Float16)v.w;
}

// xH fp16 [cell][b][64] from x[b][i][j][64]
__global__ __launch_bounds__(256) void k_prep_x(
    const float* __restrict__ x, _Float16* __restrict__ xH)
{
    int cell = blockIdx.x;              // 1024
    int i = cell >> 5, j = cell & 31;
    int b = threadIdx.x >> 2, k16 = (threadIdx.x & 3)*16;
    const float* src = &x[((b*32 + i)*32 + j)*64 + k16];
    _Float16* dst = &xH[((ull)cell*64 + b)*64 + k16];
    #pragma unroll
    for (int kk = 0; kk < 16; kk += 4) {
        float4 v = *(const float4*)&src[kk];
        dst[kk+0] = (_Float16)v.x; dst[kk+1] = (_Float16)v.y;
        dst[kk+2] = (_Float16)v.z; dst[kk+3] = (_Float16)v.w;
    }
}

// ---------------- persistent 2D-GRU wavefront (fp16 MFMA) ----------------
// 256 WGs x 512 thr. Row i -> XCD i&7; 8 WGs per row (p=0..7), each owns 32
// state channels. blk = (i&7) | p<<3 | (i>>3)<<6.
__global__ __launch_bounds__(512, 2) void k_grid(
    char* __restrict__ wsb, const float* __restrict__ bc, float* __restrict__ out)
{
    const _Float16* WtH = (const _Float16*)(wsb + OFF_WTH);
    const _Float16* WcH = (const _Float16*)(wsb + OFF_WCH);
    const float*  biasG = (const float*)(wsb + OFF_BIASG);
    const _Float16* xH  = (const _Float16*)(wsb + OFF_XH);
    float*    hcF = (float*)(wsb + OFF_HCF);
    _Float16* hcH = (_Float16*)(wsb + OFF_HCH);
    _Float16* hnX = (_Float16*)(wsb + OFF_HNX);
    int* gcnt = (int*)(wsb + OFF_FLAGS);
    int* ccnt = gcnt + 1024;

    __shared__ _Float16 As[64][328];   // staged A (k=320); later hnew[64][256]
    __shared__ float blendF[64][36];   // fp32 h state for z-blend (32 ch local)
    __shared__ float hcO[64][20];      // compress output staging (16 cols)

    const int blk = blockIdx.x;
    const int i = ((blk >> 6) << 3) | (blk & 7);
    const int p = (blk >> 3) & 7;
    const int tid = threadIdx.x;
    const int w = tid >> 6, l = tid & 63;
    const int m = w & 3, cf = w >> 2;          // gate tile coords (4m x 2cf)
    const int l15 = l & 15, lhi = l >> 4;
    const int ch = p*32 + cf*16 + l15;         // this lane's state channel
    const int chl = cf*16 + l15;               // channel local to WG
    const float bias0 = biasG[      ch], bias1 = biasG[256 + ch];
    const float bias2 = biasG[512 + ch], bias3 = biasG[768 + ch];
    const _Float16* wtR0 = WtH + (ull)(      ch)*320;
    const _Float16* wtR1 = WtH + (ull)(256 + ch)*320;
    const _Float16* wtR2 = WtH + (ull)(512 + ch)*320;
    const _Float16* wtR3 = WtH + (ull)(768 + ch)*320;
    const int ccol = p*16 + l15;               // compress out col (w<4)
    const float bcv = bc[ccol];
    half8 wcr[8];
    if (w < 4) {
        #pragma unroll
        for (int s = 0; s < 8; ++s)
            wcr[s] = *(const half8*)&WcH[(ull)ccol*256 + s*32 + lhi*8];
    }
    const int b8 = tid >> 3, q8 = tid & 7;     // staging decomposition

    for (int j = 0; j < 32; ++j) {
        const int ij = i*32 + j;
        // ---- S1: dependency polls ----
        if (tid == 0) {
            if (j > 0) while (ldrlx(&ccnt[ij - 1])  < 8) __builtin_amdgcn_s_sleep(1);
            if (i > 0) while (ldrlx(&ccnt[ij - 32]) < 8) __builtin_amdgcn_s_sleep(1);
        }
        __syncthreads();

        // ---- stage A (fp16) + blend (fp32) ----
        {   // x part: k 0..63
            *(uint4*)&As[b8][q8*8] =
                *(const uint4*)&xH[((ull)ij*64 + b8)*64 + q8*8];
            // h_row part: k 64..191  (hcH slab of row i-1)
            if (i > 0) {
                const _Float16* s = hcH + ((ull)(((i-1)&1)*32 + j)*64 + b8)*128 + q8*16;
                ull u0 = ald64(s), u1 = ald64(s+4), u2 = ald64(s+8), u3 = ald64(s+12);
                *(ull*)&As[b8][ 64 + q8*16]     = u0;
                *(ull*)&As[b8][ 64 + q8*16 + 4] = u1;
                *(ull*)&As[b8][ 64 + q8*16 + 8] = u2;
                *(ull*)&As[b8][ 64 + q8*16 +12] = u3;
            } else {
                *(ull*)&As[b8][ 64 + q8*16]     = 0ull;
                *(ull*)&As[b8][ 64 + q8*16 + 4] = 0ull;
                *(ull*)&As[b8][ 64 + q8*16 + 8] = 0ull;
                *(ull*)&As[b8][ 64 + q8*16 +12] = 0ull;
            }
            // h_col part: k 192..319 (hcH slab of own row, col j-1)
            if (j > 0) {
                const _Float16* s = hcH + ((ull)((i&1)*32 + (j-1))*64 + b8)*128 + q8*16;
                ull u0 = ald64(s), u1 = ald64(s+4), u2 = ald64(s+8), u3 = ald64(s+12);
                *(ull*)&As[b8][192 + q8*16]     = u0;
                *(ull*)&As[b8][192 + q8*16 + 4] = u1;
                *(ull*)&As[b8][192 + q8*16 + 8] = u2;
                *(ull*)&As[b8][192 + q8*16 +12] = u3;
            } else {
                *(ull*)&As[b8][192 + q8*16]     = 0ull;
                *(ull*)&As[b8][192 + q8*16 + 4] = 0ull;
                *(ull*)&As[b8][192 + q8*16 + 8] = 0ull;
                *(ull*)&As[b8][192 + q8*16 +12] = 0ull;
            }
            // blend fp32: WG's 32 channels of the h state
            bool valid; const float* s;
            if (p < 4) { valid = (i > 0);
                s = hcF + ((ull)(((i-1)&1)*32 + j)*64 + b8)*128 + p*32 + q8*4; }
            else       { valid = (j > 0);
                s = hcF + ((ull)((i&1)*32 + (j-1))*64 + b8)*128 + (p-4)*32 + q8*4; }
            ull u0 = valid ? ald64(s) : 0ull;
            ull u1 = valid ? ald64(s + 2) : 0ull;
            *(ull*)&blendF[b8][q8*4]     = u0;
            *(ull*)&blendF[b8][q8*4 + 2] = u1;
        }
        __syncthreads();   // S2

        // ---- gate GEMM: 4 gate tiles per wave, K=320 ----
        f32x4 a0 = {bias0,bias0,bias0,bias0};
        f32x4 a1 = {bias1,bias1,bias1,bias1};
        f32x4 a2 = {bias2,bias2,bias2,bias2};
        f32x4 a3 = {bias3,bias3,bias3,bias3};
        {
            const int arow = m*16 + l15;
            const int ko = lhi*8;
            #pragma unroll
            for (int ks = 0; ks < 10; ++ks) {
                half8 a  = *(const half8*)&As[arow][ks*32 + ko];
                half8 b0 = *(const half8*)&wtR0[ks*32 + ko];
                half8 b1 = *(const half8*)&wtR1[ks*32 + ko];
                half8 b2 = *(const half8*)&wtR2[ks*32 + ko];
                half8 b3 = *(const half8*)&wtR3[ks*32 + ko];
                a0 = __builtin_amdgcn_mfma_f32_16x16x32_f16(a, b0, a0, 0, 0, 0);
                a1 = __builtin_amdgcn_mfma_f32_16x16x32_f16(a, b1, a1, 0, 0, 0);
                a2 = __builtin_amdgcn_mfma_f32_16x16x32_f16(a, b2, a2, 0, 0, 0);
                a3 = __builtin_amdgcn_mfma_f32_16x16x32_f16(a, b3, a3, 0, 0, 0);
            }
        }
        // ---- gates (in-lane; D rows = m*16 + lhi*4 + r, col = ch) ----
        float hn[4];
        #pragma unroll
        for (int r = 0; r < 4; ++r) {
            float rg = 1.f/(1.f + __expf(-a0[r]));
            float zg = 1.f/(1.f + __expf(-a1[r]));
            float e2 = __expf(2.f*(a2[r] + rg*a3[r]));
            float ng = 1.f - 2.f/(e2 + 1.f);
            float hv = blendF[m*16 + lhi*4 + r][chl];
            hn[r] = (1.f - zg)*ng + zg*hv;
        }
        __syncthreads();   // S3: all gate A-reads done
        #pragma unroll
        for (int r = 0; r < 4; ++r)
            As[m*16 + lhi*4 + r][ch] = (_Float16)hn[r];   // hnew into A region
        __syncthreads();   // S4
        // ---- own hnew slab -> global (for siblings) ----
        {
            _Float16* dst = hnX + ((ull)(i*2 + (j&1))*64 + b8)*256 + p*32 + q8*4;
            ast64(dst, *(const ull*)&As[b8][p*32 + q8*4]);
        }
        __syncthreads();   // S5: slab stores drained
        if (tid == 0) {
            __hip_atomic_fetch_add(&gcnt[ij], 1, __ATOMIC_ACQ_REL, __HIP_MEMORY_SCOPE_AGENT);
            while (ldrlx(&gcnt[ij]) < 8) __builtin_amdgcn_s_sleep(1);
        }
        __syncthreads();   // S6
        // ---- read 7 sibling slabs -> As ----
        #pragma unroll
        for (int pp = 0; pp < 8; ++pp) {
            if (pp == p) continue;
            const _Float16* s = hnX + ((ull)(i*2 + (j&1))*64 + b8)*256 + pp*32 + q8*4;
            *(ull*)&As[b8][pp*32 + q8*4] = ald64(s);
        }
        __syncthreads();   // S7
        // ---- compress: waves 0..3, one 16x16 tile each (m=w, cols p*16..) ----
        if (w < 4) {
            f32x4 c2 = {bcv, bcv, bcv, bcv};
            const int arow = w*16 + l15;
            const int ko = lhi*8;
            #pragma unroll
            for (int s = 0; s < 8; ++s) {
                half8 a = *(const half8*)&As[arow][s*32 + ko];
                c2 = __builtin_amdgcn_mfma_f32_16x16x32_f16(a, wcr[s], c2, 0, 0, 0);
            }
            #pragma unroll
            for (int r = 0; r < 4; ++r)
                hcO[w*16 + lhi*4 + r][l15] = c2[r];
        }
        __syncthreads();   // S8
        // ---- hc(i,j) -> global (fp32 + fp16), coalesced ----
        {
            const int c2i = q8*2;
            float v0 = hcO[b8][c2i], v1 = hcO[b8][c2i + 1];
            ull uf; ((float*)&uf)[0] = v0; ((float*)&uf)[1] = v1;
            ast64(hcF + ((ull)((i&1)*32 + j)*64 + b8)*128 + p*16 + c2i, uf);
            union { _Float16 h[2]; unsigned u; } uh;
            uh.h[0] = (_Float16)v0; uh.h[1] = (_Float16)v1;
            ast32u(hcH + ((ull)((i&1)*32 + j)*64 + b8)*128 + p*16 + c2i, uh.u);
            if (ij == 1023) {
                out[b8*128 + p*16 + c2i]     = v0;
                out[b8*128 + p*16 + c2i + 1] = v1;
            }
        }
        __syncthreads();   // S9: hc stores drained
        if (tid == 0)
            __hip_atomic_fetch_add(&ccnt[ij], 1, __ATOMIC_ACQ_REL, __HIP_MEMORY_SCOPE_AGENT);
    }
}

extern "C" void kernel_launch(void* const* d_in, const int* in_sizes, int n_in,
                              void* d_out, int out_size, void* d_ws, size_t ws_size,
                              hipStream_t stream)
{
    const float* x    = (const float*)d_in[0];
    const float* We   = (const float*)d_in[1];
    const float* be   = (const float*)d_in[2];
    const float* W_ih = (const float*)d_in[3];
    const float* b_ih = (const float*)d_in[4];
    const float* W_hh = (const float*)d_in[5];
    const float* b_hh = (const float*)d_in[6];
    const float* Wc   = (const float*)d_in[7];
    const float* bc   = (const float*)d_in[8];
    char* wsb = (char*)d_ws;
    float* Wx       = (float*)(wsb + OFF_WX);
    _Float16* WtH   = (_Float16*)(wsb + OFF_WTH);
    _Float16* WcHp  = (_Float16*)(wsb + OFF_WCH);
    float* biasG    = (float*)(wsb + OFF_BIASG);
    _Float16* xH    = (_Float16*)(wsb + OFF_XH);
    int* flags      = (int*)(wsb + OFF_FLAGS);
    float* out      = (float*)d_out;

    k_build_wx<<<192, 256, 0, stream>>>(W_ih, We, Wx);
    k_prep_wt<<<1024, 256, 0, stream>>>(Wx, W_hh, WtH);
    k_prep_bias<<<4, 256, 0, stream>>>(b_ih, b_hh, W_ih, be, biasG);
    k_prep_wc<<<32, 256, 0, stream>>>(Wc, WcHp);
    k_prep_x<<<1024, 256, 0, stream>>>(x, xH);
    hipMemsetAsync(flags, 0, 2048*sizeof(int), stream);
    k_grid<<<256, 512, 0, stream>>>(wsb, bc, out);
}